// Round 18
// baseline (263.361 us; speedup 1.0000x reference)
//
#include <hip/hip_runtime.h>
#include <math.h>

#define NB 4
#define NC 64
#define NL 1024   // 32x32 kernel-patch grid
#define NP 3969   // 63x63 correlation positions
#define PHW 63

typedef unsigned short ushort_t;
typedef __attribute__((ext_vector_type(8))) short short8;
typedef __attribute__((ext_vector_type(16))) float floatx16;

// A' per b: 32 rtiles * 64 kchunks * 64 lanes * 8 = 2^20 ushorts
#define A_BSTRIDE 1048576
// B' per b: 128 rtiles (4096 rows, padded for 256-wide p-tiles) * 64 * 512
#define B_BSTRIDE 4194304

// ---------------- kernel 1: fused prep = norm + stats + padB --------------
__global__ __launch_bounds__(256) void prep_kernel(const float* __restrict__ bsrc,
                                                   const float* __restrict__ mask,
                                                   float* __restrict__ invn,
                                                   float* __restrict__ mmk,
                                                   float* __restrict__ mmp,
                                                   ushort_t* __restrict__ Bhi,
                                                   ushort_t* __restrict__ Blo) {
    int blk = blockIdx.x;
    if (blk < 256) {
        const float* src = bsrc + (size_t)blk * 4096;
        float s = 0.f;
        for (int i = threadIdx.x; i < 4096; i += 256) { float v = src[i]; s += v * v; }
#pragma unroll
        for (int off = 32; off > 0; off >>= 1) s += __shfl_down(s, off, 64);
        __shared__ float part[4];
        if ((threadIdx.x & 63) == 0) part[threadIdx.x >> 6] = s;
        __syncthreads();
        if (threadIdx.x == 0) {
            float t = part[0] + part[1] + part[2] + part[3];
            invn[blk] = 1.0f / sqrtf(t + 1e-8f);
        }
    } else if (blk < 335) {
        int id = (blk - 256) * 256 + threadIdx.x;
        if (id < NB * NL) {
            int b = id >> 10, l = id & 1023;
            int lh = l >> 5, lw = l & 31;
            const float* m = mask + b * 4096;
            float s = 0.f;
#pragma unroll
            for (int i = 0; i < 4; ++i) {
                int r = min(max(2 * lh - 1 + i, 0), 63);
#pragma unroll
                for (int j = 0; j < 4; ++j) {
                    int c = min(max(2 * lw - 1 + j, 0), 63);
                    s += 1.0f - m[r * 64 + c];
                }
            }
            mmk[id] = s * (1.0f / 16.0f);
        } else {
            int id2 = id - NB * NL;
            if (id2 < NB * NP) {
                int b = id2 / NP, p = id2 - b * NP;
                int ph = p / PHW, pw = p - ph * PHW;
                const float* m = mask + b * 4096;
                float s = 0.f;
#pragma unroll
                for (int i = 0; i < 4; ++i) {
                    int r = min(max(ph - 1 + i, 0), 63);
#pragma unroll
                    for (int j = 0; j < 4; ++j) {
                        int c = min(max(pw - 1 + j, 0), 63);
                        s += 1.0f - m[r * 64 + c];
                    }
                }
                mmp[id2] = s * (1.0f / 16.0f);
            }
        }
    } else {
        // zero rtiles 124..127 (rows 3968..4095) for all b, both matrices
        int idx = (blk - 335) * 256 + threadIdx.x;   // 0..131071
        int b = idx >> 15;
        int r = idx & 32767;
        int mat = r >> 14;
        int o = r & 16383;
        ushort_t* base = (mat ? Blo : Bhi) + (size_t)b * B_BSTRIDE + 124 * 32768;
        uint4 z = {0u, 0u, 0u, 0u};
        ((uint4*)base)[o] = z;
    }
}

// ------------- split helper: fp32 -> bf16 hi + bf16 residual --------------
__device__ inline void split_bf16(float v, ushort_t& hv, ushort_t& lv) {
    unsigned u = __float_as_uint(v);
    unsigned rr = u + 0x7FFFu + ((u >> 16) & 1u);
    hv = (ushort_t)(rr >> 16);
    float fh = __uint_as_float(((unsigned)hv) << 16);
    float remv = v - fh;
    unsigned u2 = __float_as_uint(remv);
    unsigned rr2 = u2 + 0x7FFFu + ((u2 >> 16) & 1u);
    lv = (ushort_t)(rr2 >> 16);
}

// fragment-order address for (row, kchunk)
__device__ inline int frag_addr(int row, int kc) {
    return ((row >> 5) * 64 + kc) * 512 + (row & 31) * 8;
}

// --------- kernel 3: merged splitA (x<32) + splitB (x>=32) ---------------
__global__ __launch_bounds__(256) void split_kernel(const float* __restrict__ bsrc,
                                                    const float* __restrict__ invn,
                                                    ushort_t* __restrict__ Ahi,
                                                    ushort_t* __restrict__ Alo,
                                                    const float* __restrict__ fsrc,
                                                    ushort_t* __restrict__ Bhi,
                                                    ushort_t* __restrict__ Blo) {
    __shared__ float fl[32 * 257];
    int x = blockIdx.x, b = blockIdx.y, chalf = blockIdx.z;
    int t = threadIdx.x;
    if (x < 32) {
        int lh = x;
#pragma unroll
        for (int q = 0; q < 32; ++q) {
            int idx = t + (q << 8);
            int cl = idx >> 8, rem = idx & 255;
            int i = rem >> 6, s = rem & 63;
            int c = (chalf << 5) + cl;
            int r = min(max(2 * lh - 1 + i, 0), 63);
            fl[cl * 257 + rem] = bsrc[(((size_t)((b << 6) + c)) << 12) + (r << 6) + s];
        }
        __syncthreads();
        ushort_t* Ah = Ahi + (size_t)b * A_BSTRIDE;
        ushort_t* Al = Alo + (size_t)b * A_BSTRIDE;
#pragma unroll
        for (int q = 0; q < 4; ++q) {
            int pair = t + (q << 8);         // 0..1023
            int lw = pair & 31, cl = pair >> 5;
            int c = (chalf << 5) + cl;
            float scale = invn[(b << 6) + c];
            const float* row = fl + cl * 257;
            __align__(16) ushort_t h[16];
            __align__(16) ushort_t lo[16];
#pragma unroll
            for (int i = 0; i < 4; ++i)
#pragma unroll
                for (int j = 0; j < 4; ++j) {
                    int s = min(max(2 * lw - 1 + j, 0), 63);
                    split_bf16(row[i * 64 + s] * scale, h[i * 4 + j], lo[i * 4 + j]);
                }
            int a = (lh * 64 + c) * 512 + lw * 8;
            *(uint4*)(Ah + a)       = *(uint4*)h;
            *(uint4*)(Ah + a + 256) = *(uint4*)(h + 8);
            *(uint4*)(Al + a)       = *(uint4*)lo;
            *(uint4*)(Al + a + 256) = *(uint4*)(lo + 8);
        }
    } else {
        int ph = x - 32;
#pragma unroll
        for (int q = 0; q < 32; ++q) {
            int idx = t + (q << 8);
            int cl = idx >> 8, rem = idx & 255;
            int i = rem >> 6, s = rem & 63;
            int c = (chalf << 5) + cl;
            int r = min(max(ph - 1 + i, 0), 63);
            fl[cl * 257 + rem] = fsrc[(((size_t)((b << 6) + c)) << 12) + (r << 6) + s];
        }
        __syncthreads();
        ushort_t* Bh = Bhi + (size_t)b * B_BSTRIDE;
        ushort_t* Bl = Blo + (size_t)b * B_BSTRIDE;
#pragma unroll
        for (int q = 0; q < 8; ++q) {
            int pair = t + (q << 8);          // 0..2047
            int pw = pair & 63, cl = pair >> 6;
            if (pw < PHW) {
                int c = (chalf << 5) + cl;
                const float* row = fl + cl * 257;
                __align__(16) ushort_t h[16];
                __align__(16) ushort_t lo[16];
#pragma unroll
                for (int i = 0; i < 4; ++i)
#pragma unroll
                    for (int j = 0; j < 4; ++j) {
                        int s = min(max(pw - 1 + j, 0), 63);
                        split_bf16(row[i * 64 + s], h[i * 4 + j], lo[i * 4 + j]);
                    }
                int p = ph * PHW + pw;
                int a = frag_addr(p, c);
                *(uint4*)(Bh + a)       = *(uint4*)h;
                *(uint4*)(Bh + a + 256) = *(uint4*)(h + 8);
                *(uint4*)(Bl + a)       = *(uint4*)lo;
                *(uint4*)(Bl + a + 256) = *(uint4*)(lo + 8);
            }
        }
    }
}

// ---- kernel 4: 128x256-tile, 4-wave GEMM; A via LDS, B global->regs ------
// Identical to the measured R17 best, plus anti-phase-lock stagger: the
// second half of the grid (likely co-resident partners) sleeps ~1600 cyc
// (half a chunk period) at entry so the two blocks sharing a CU alternate
// load/MFMA phases instead of colliding at the barriers. Zero FP change.
__global__ __launch_bounds__(256, 2) void gemm_kernel(
    const ushort_t* __restrict__ Ahi, const ushort_t* __restrict__ Alo,
    const ushort_t* __restrict__ Bhi, const ushort_t* __restrict__ Blo,
    float* __restrict__ Rt) {
    __shared__ ushort_t smem[2][8][512];       // [buf][seg: 0-3 Ahi rt, 4-7 Alo rt][512]
    int tid = threadIdx.x;
    int lane = tid & 63, w = tid >> 6;         // w = 0..3 (p-wave)
    int bid = blockIdx.x;                      // 0..511
    int wid = ((bid & 7) << 6) + (bid >> 3);   // bijective XCD-chunk remap
    int b = wid >> 7;
    int rem = wid & 127;
    int lg = rem >> 4;                         // 0..7  : L0 = lg*128
    int pg = rem & 15;                         // 0..15 : P0 = pg*256
    int L0 = lg << 7, P0 = pg << 8;

    if (bid & 256) __builtin_amdgcn_s_sleep(25);   // ~1600 cyc de-phase

    // A staging sources: wave w stages segs {2w, 2w+1}
    const ushort_t* asrc[2];
#pragma unroll
    for (int i = 0; i < 2; ++i) {
        int s = 2 * w + i;
        const ushort_t* base = ((s >> 2) ? Alo : Ahi) + (size_t)b * A_BSTRIDE;
        asrc[i] = base + (size_t)((L0 >> 5) + (s & 3)) * 32768 + (size_t)(lane << 3);
    }
    ushort_t* dst0 = &smem[0][2 * w][0];
    ushort_t* dst1 = &smem[1][2 * w][0];

    // B direct-load sources: [0]=Bhi pt0, [1]=Bhi pt1, [2]=Blo pt0, [3]=Blo pt1
    const ushort_t* bsrc[4];
#pragma unroll
    for (int i = 0; i < 4; ++i) {
        const ushort_t* base = ((i >> 1) ? Blo : Bhi) + (size_t)b * B_BSTRIDE;
        bsrc[i] = base + (size_t)((P0 >> 5) + 2 * w + (i & 1)) * 32768 + (size_t)(lane << 3);
    }

#define STAGEA(dstp, kc)                                                                   \
    do {                                                                                   \
        _Pragma("unroll")                                                                  \
        for (int i = 0; i < 2; ++i)                                                        \
            __builtin_amdgcn_global_load_lds(                                              \
                (const __attribute__((address_space(1))) void*)(asrc[i] + (size_t)(kc) * 512), \
                (__attribute__((address_space(3))) void*)((dstp) + i * 512),               \
                16, 0, 0);                                                                 \
    } while (0)

#define LOADB(dst, kc)                                                    \
    do {                                                                  \
        _Pragma("unroll")                                                 \
        for (int i = 0; i < 4; ++i)                                       \
            dst[i] = *(const short8*)(bsrc[i] + (size_t)(kc) * 512);      \
    } while (0)

#define COMP(bufi, bf)                                                                     \
    do {                                                                                   \
        _Pragma("unroll")                                                                  \
        for (int lt = 0; lt < 4; ++lt) {                                                   \
            short8 ahf = *(const short8*)(&smem[bufi][lt][lane << 3]);                     \
            short8 alf = *(const short8*)(&smem[bufi][4 + lt][lane << 3]);                 \
            __builtin_amdgcn_s_setprio(1);                                                 \
            _Pragma("unroll")                                                              \
            for (int pt = 0; pt < 2; ++pt) {                                               \
                acc[pt][lt] = __builtin_amdgcn_mfma_f32_32x32x16_bf16(bf[pt], ahf, acc[pt][lt], 0, 0, 0);     \
                acc[pt][lt] = __builtin_amdgcn_mfma_f32_32x32x16_bf16(bf[pt], alf, acc[pt][lt], 0, 0, 0);     \
                acc[pt][lt] = __builtin_amdgcn_mfma_f32_32x32x16_bf16(bf[2 + pt], ahf, acc[pt][lt], 0, 0, 0); \
            }                                                                              \
            __builtin_amdgcn_s_setprio(0);                                                 \
        }                                                                                  \
    } while (0)

    floatx16 acc[2][4];
#pragma unroll
    for (int i = 0; i < 2; ++i)
#pragma unroll
        for (int j = 0; j < 4; ++j)
#pragma unroll
            for (int r = 0; r < 16; ++r) acc[i][j][r] = 0.f;

    short8 bB0[4], bB1[4];
    LOADB(bB0, 0);                             // chunk 0 B -> regs   (4 vm ops)
    STAGEA(dst0, 0);                           // chunk 0 A -> LDS    (2 vm ops)

    for (int t = 0; t < 64; t += 2) {
        // ---- even chunk t: buf0 / bB0 ----
        LOADB(bB1, t + 1);                     // next B (4)
        STAGEA(dst1, t + 1);                   // next A (2)
        asm volatile("s_waitcnt vmcnt(6)" ::: "memory");   // chunk t landed
        __builtin_amdgcn_s_barrier();
        asm volatile("" ::: "memory");
        COMP(0, bB0);
        asm volatile("" ::: "memory");
        __builtin_amdgcn_s_barrier();
        // ---- odd chunk t+1: buf1 / bB1 ----
        if (t + 2 < 64) {
            LOADB(bB0, t + 2);
            STAGEA(dst0, t + 2);
            asm volatile("s_waitcnt vmcnt(6)" ::: "memory");
        } else {
            asm volatile("s_waitcnt vmcnt(0)" ::: "memory");
        }
        __builtin_amdgcn_s_barrier();
        asm volatile("" ::: "memory");
        COMP(1, bB1);
        asm volatile("" ::: "memory");
        __builtin_amdgcn_s_barrier();
    }
#undef STAGEA
#undef LOADB
#undef COMP

    int x = lane & 31, kg = lane >> 5;
    int pw0 = P0 + (w << 6);
#pragma unroll
    for (int pt = 0; pt < 2; ++pt)
#pragma unroll
        for (int lt = 0; lt < 4; ++lt)
#pragma unroll
            for (int r = 0; r < 16; ++r) {
                int p = pw0 + (pt << 5) + (r & 3) + ((r >> 2) << 3) + (kg << 2);
                int l = L0 + (lt << 5) + x;
                if (p < NP) Rt[((size_t)b * NP + p) * NL + l] = acc[pt][lt][r];
            }
}

// ------- kernel 5: fused diag1 + diag2 + mask + softmax, row output -------
// (verified R8 per-p version: best measured non-GEMM config)
__global__ __launch_bounds__(256) void softmax_fused_kernel(const float* __restrict__ Rt,
                                                            const float* __restrict__ mmkA,
                                                            const float* __restrict__ mmpA,
                                                            float* __restrict__ E) {
    __shared__ float ld0[1024], ld1[1024], ld2[1024];
    __shared__ float red[8];
    int p = blockIdx.x, b = blockIdx.y;
    int ph = p / PHW, pw = p - ph * PHW;
    int t = threadIdx.x;
    int lane = t & 63, w = t >> 6;
    int l0 = t << 2;

    bool okm = (p != 0), okp = (p != 3968);
    int Pm = (ph > 0) ? p - 63 : 3905 + pw;
    int Pp = (ph < 62) ? p + 63 : pw + 1;

    const float* Rb = Rt + (size_t)b * NP * NL;
#define BUILD(dst, q)                                                   \
    do {                                                                \
        const float* base = Rb + (size_t)(q) * NL;                      \
        float4 r = *(const float4*)(base + l0);                         \
        if ((q) > 0) {                                                  \
            const float* pm = base - NL;                                \
            r.x += (l0 > 0) ? pm[l0 - 1] : 0.f;                         \
            r.y += pm[l0];  r.z += pm[l0 + 1];  r.w += pm[l0 + 2];      \
        }                                                               \
        if ((q) < NP - 1) {                                             \
            const float* pp = base + NL;                                \
            r.x += pp[l0 + 1];  r.y += pp[l0 + 2];  r.z += pp[l0 + 3];  \
            r.w += (l0 + 4 < NL) ? pp[l0 + 4] : 0.f;                    \
        }                                                               \
        *(float4*)(dst + l0) = r;                                       \
    } while (0)

    BUILD(ld0, p);
    if (okm) BUILD(ld1, Pm);
    if (okp) BUILD(ld2, Pp);
#undef BUILD
    __syncthreads();

    float4 vc = *(const float4*)(ld0 + l0);
    float4 vm = {0.f, 0.f, 0.f, 0.f}, vp = {0.f, 0.f, 0.f, 0.f};
    if (okm) {
        if (l0 >= 32) vm = *(const float4*)(ld1 + l0 - 32);
        else {
            vm.x = (l0 == 0) ? 0.f : ld1[l0 + 991];
            vm.y = ld1[l0 + 992];
            vm.z = ld1[l0 + 993];
            vm.w = ld1[l0 + 994];
        }
    }
    if (okp) {
        if (l0 < 992) vp = *(const float4*)(ld2 + l0 + 32);
        else {
            vp.x = ld2[l0 - 991];
            vp.y = ld2[l0 - 990];
            vp.z = ld2[l0 - 989];
            vp.w = (l0 + 3 == 1023) ? 0.f : ld2[l0 - 988];
        }
    }
    float mmpv = mmpA[b * NP + p];
    float4 km = *(const float4*)(mmkA + b * NL + l0);
    float lg[4];
    float fsum[4] = {vc.x + vm.x + vp.x, vc.y + vm.y + vp.y,
                     vc.z + vm.z + vp.z, vc.w + vm.w + vp.w};
    float kk[4] = {km.x, km.y, km.z, km.w};
#pragma unroll
    for (int i = 0; i < 4; ++i) {
        float mmv = (((kk[i] > mmpv) && (mmpv > 0.5f)) || (kk[i] == 1.0f)) ? 1.0f : 0.0f;
        lg[i] = fsum[i] * mmv * 10.0f;
    }
    float mx = fmaxf(fmaxf(lg[0], lg[1]), fmaxf(lg[2], lg[3]));
#pragma unroll
    for (int off = 32; off >= 1; off >>= 1) mx = fmaxf(mx, __shfl_xor(mx, off, 64));
    if (lane == 0) red[w] = mx;
    __syncthreads();
    mx = fmaxf(fmaxf(red[0], red[1]), fmaxf(red[2], red[3]));
    float e[4];
    float s = 0.f;
#pragma unroll
    for (int i = 0; i < 4; ++i) { e[i] = expf(lg[i] - mx); s += e[i]; }
#pragma unroll
    for (int off = 32; off >= 1; off >>= 1) s += __shfl_xor(s, off, 64);
    if (lane == 0) red[4 + w] = s;
    __syncthreads();
    float rinv = 1.0f / (red[4] + red[5] + red[6] + red[7]);
    float4 ev = {e[0] * rinv, e[1] * rinv, e[2] * rinv, e[3] * rinv};
    *(float4*)(E + (((size_t)b * NP + p) << 10) + l0) = ev;
}

// ---------------- kernel 6: tiled transpose E[p][l] -> out[l][p] ----------
__global__ __launch_bounds__(256) void transpose_kernel(const float* __restrict__ E,
                                                        float* __restrict__ out) {
    __shared__ float tile[63 * 65];
    int pt = blockIdx.x;       // 0..62 : p0 = pt*63
    int lt = blockIdx.y;       // 0..15 : l0 = lt*64
    int b  = blockIdx.z;
    int t = threadIdx.x;
    int p0 = pt * 63, l0 = lt << 6;
    const float* Eb = E + ((size_t)b * NP << 10);
    {
        int j = t & 63, i4 = t >> 6;
#pragma unroll
        for (int k = 0; k < 16; ++k) {
            int i = (k << 2) + i4;
            if (i < 63) tile[i * 65 + j] = Eb[((size_t)(p0 + i) << 10) + l0 + j];
        }
    }
    __syncthreads();
    {
        int ii = t & 63, jj4 = t >> 6;
        if (ii < 63) {
#pragma unroll
            for (int k = 0; k < 16; ++k) {
                int jj = (k << 2) + jj4;
                out[((size_t)b * NL + l0 + jj) * NP + p0 + ii] = tile[ii * 65 + jj];
            }
        }
    }
}

extern "C" void kernel_launch(void* const* d_in, const int* in_sizes, int n_in,
                              void* d_out, int out_size, void* d_ws, size_t ws_size,
                              hipStream_t stream) {
    const float* f    = (const float*)d_in[0];
    const float* b    = (const float*)d_in[1];
    const float* mask = (const float*)d_in[2];
    float* out = (float*)d_out;

    // Rt lives in d_out (consumed by softmax before transpose overwrites out).
    float* Rt = (float*)d_out;

    // ws layout (floats): E at [16257024 .. 32514048); stats after.
    // A'/B' (~84 MB) occupy ws from 0 but are dead post-GEMM.
    float* wsf = (float*)d_ws;
    float* E  = wsf + 16257024;
    ushort_t* Ahi = (ushort_t*)d_ws;
    ushort_t* Alo = Ahi + (size_t)NB * A_BSTRIDE;
    ushort_t* Bhi = Alo + (size_t)NB * A_BSTRIDE;
    ushort_t* Blo = Bhi + (size_t)NB * B_BSTRIDE;
    float* invn = wsf + 32514048;
    float* mmk = invn + 256;
    float* mmp = mmk + 4096;

    prep_kernel<<<dim3(847), dim3(256), 0, stream>>>(b, mask, invn, mmk, mmp, Bhi, Blo);
    split_kernel<<<dim3(95, 4, 2), dim3(256), 0, stream>>>(b, invn, Ahi, Alo, f, Bhi, Blo);
    gemm_kernel<<<dim3(512), dim3(256), 0, stream>>>(Ahi, Alo, Bhi, Blo, Rt);
    softmax_fused_kernel<<<dim3(3969, 4), dim3(256), 0, stream>>>(Rt, mmk, mmp, E);
    transpose_kernel<<<dim3(63, 16, 4), dim3(256), 0, stream>>>(E, out);
}

// Round 19
// 263.188 us; speedup vs baseline: 1.0007x; 1.0007x over previous
//
#include <hip/hip_runtime.h>
#include <math.h>

#define NB 4
#define NC 64
#define NL 1024   // 32x32 kernel-patch grid
#define NP 3969   // 63x63 correlation positions
#define PHW 63

typedef unsigned short ushort_t;
typedef __attribute__((ext_vector_type(8))) short short8;
typedef __attribute__((ext_vector_type(16))) float floatx16;

// A' per b: 32 rtiles * 64 kchunks * 64 lanes * 8 = 2^20 ushorts
#define A_BSTRIDE 1048576
// B' per b: 128 rtiles (4096 rows, padded for 256-wide p-tiles) * 64 * 512
#define B_BSTRIDE 4194304

// ---------------- kernel 1: fused prep = norm + stats + padB --------------
__global__ __launch_bounds__(256) void prep_kernel(const float* __restrict__ bsrc,
                                                   const float* __restrict__ mask,
                                                   float* __restrict__ invn,
                                                   float* __restrict__ mmk,
                                                   float* __restrict__ mmp,
                                                   ushort_t* __restrict__ Bhi,
                                                   ushort_t* __restrict__ Blo) {
    int blk = blockIdx.x;
    if (blk < 256) {
        const float* src = bsrc + (size_t)blk * 4096;
        float s = 0.f;
        for (int i = threadIdx.x; i < 4096; i += 256) { float v = src[i]; s += v * v; }
#pragma unroll
        for (int off = 32; off > 0; off >>= 1) s += __shfl_down(s, off, 64);
        __shared__ float part[4];
        if ((threadIdx.x & 63) == 0) part[threadIdx.x >> 6] = s;
        __syncthreads();
        if (threadIdx.x == 0) {
            float t = part[0] + part[1] + part[2] + part[3];
            invn[blk] = 1.0f / sqrtf(t + 1e-8f);
        }
    } else if (blk < 335) {
        int id = (blk - 256) * 256 + threadIdx.x;
        if (id < NB * NL) {
            int b = id >> 10, l = id & 1023;
            int lh = l >> 5, lw = l & 31;
            const float* m = mask + b * 4096;
            float s = 0.f;
#pragma unroll
            for (int i = 0; i < 4; ++i) {
                int r = min(max(2 * lh - 1 + i, 0), 63);
#pragma unroll
                for (int j = 0; j < 4; ++j) {
                    int c = min(max(2 * lw - 1 + j, 0), 63);
                    s += 1.0f - m[r * 64 + c];
                }
            }
            mmk[id] = s * (1.0f / 16.0f);
        } else {
            int id2 = id - NB * NL;
            if (id2 < NB * NP) {
                int b = id2 / NP, p = id2 - b * NP;
                int ph = p / PHW, pw = p - ph * PHW;
                const float* m = mask + b * 4096;
                float s = 0.f;
#pragma unroll
                for (int i = 0; i < 4; ++i) {
                    int r = min(max(ph - 1 + i, 0), 63);
#pragma unroll
                    for (int j = 0; j < 4; ++j) {
                        int c = min(max(pw - 1 + j, 0), 63);
                        s += 1.0f - m[r * 64 + c];
                    }
                }
                mmp[id2] = s * (1.0f / 16.0f);
            }
        }
    } else {
        // zero rtiles 124..127 (rows 3968..4095) for all b, both matrices
        int idx = (blk - 335) * 256 + threadIdx.x;   // 0..131071
        int b = idx >> 15;
        int r = idx & 32767;
        int mat = r >> 14;
        int o = r & 16383;
        ushort_t* base = (mat ? Blo : Bhi) + (size_t)b * B_BSTRIDE + 124 * 32768;
        uint4 z = {0u, 0u, 0u, 0u};
        ((uint4*)base)[o] = z;
    }
}

// ------------- split helper: fp32 -> bf16 hi + bf16 residual --------------
__device__ inline void split_bf16(float v, ushort_t& hv, ushort_t& lv) {
    unsigned u = __float_as_uint(v);
    unsigned rr = u + 0x7FFFu + ((u >> 16) & 1u);
    hv = (ushort_t)(rr >> 16);
    float fh = __uint_as_float(((unsigned)hv) << 16);
    float remv = v - fh;
    unsigned u2 = __float_as_uint(remv);
    unsigned rr2 = u2 + 0x7FFFu + ((u2 >> 16) & 1u);
    lv = (ushort_t)(rr2 >> 16);
}

// fragment-order address for (row, kchunk)
__device__ inline int frag_addr(int row, int kc) {
    return ((row >> 5) * 64 + kc) * 512 + (row & 31) * 8;
}

// --------- kernel 3: merged splitA (x<32) + splitB (x>=32) ---------------
__global__ __launch_bounds__(256) void split_kernel(const float* __restrict__ bsrc,
                                                    const float* __restrict__ invn,
                                                    ushort_t* __restrict__ Ahi,
                                                    ushort_t* __restrict__ Alo,
                                                    const float* __restrict__ fsrc,
                                                    ushort_t* __restrict__ Bhi,
                                                    ushort_t* __restrict__ Blo) {
    __shared__ float fl[32 * 257];
    int x = blockIdx.x, b = blockIdx.y, chalf = blockIdx.z;
    int t = threadIdx.x;
    if (x < 32) {
        int lh = x;
#pragma unroll
        for (int q = 0; q < 32; ++q) {
            int idx = t + (q << 8);
            int cl = idx >> 8, rem = idx & 255;
            int i = rem >> 6, s = rem & 63;
            int c = (chalf << 5) + cl;
            int r = min(max(2 * lh - 1 + i, 0), 63);
            fl[cl * 257 + rem] = bsrc[(((size_t)((b << 6) + c)) << 12) + (r << 6) + s];
        }
        __syncthreads();
        ushort_t* Ah = Ahi + (size_t)b * A_BSTRIDE;
        ushort_t* Al = Alo + (size_t)b * A_BSTRIDE;
#pragma unroll
        for (int q = 0; q < 4; ++q) {
            int pair = t + (q << 8);         // 0..1023
            int lw = pair & 31, cl = pair >> 5;
            int c = (chalf << 5) + cl;
            float scale = invn[(b << 6) + c];
            const float* row = fl + cl * 257;
            __align__(16) ushort_t h[16];
            __align__(16) ushort_t lo[16];
#pragma unroll
            for (int i = 0; i < 4; ++i)
#pragma unroll
                for (int j = 0; j < 4; ++j) {
                    int s = min(max(2 * lw - 1 + j, 0), 63);
                    split_bf16(row[i * 64 + s] * scale, h[i * 4 + j], lo[i * 4 + j]);
                }
            int a = (lh * 64 + c) * 512 + lw * 8;
            *(uint4*)(Ah + a)       = *(uint4*)h;
            *(uint4*)(Ah + a + 256) = *(uint4*)(h + 8);
            *(uint4*)(Al + a)       = *(uint4*)lo;
            *(uint4*)(Al + a + 256) = *(uint4*)(lo + 8);
        }
    } else {
        int ph = x - 32;
#pragma unroll
        for (int q = 0; q < 32; ++q) {
            int idx = t + (q << 8);
            int cl = idx >> 8, rem = idx & 255;
            int i = rem >> 6, s = rem & 63;
            int c = (chalf << 5) + cl;
            int r = min(max(ph - 1 + i, 0), 63);
            fl[cl * 257 + rem] = fsrc[(((size_t)((b << 6) + c)) << 12) + (r << 6) + s];
        }
        __syncthreads();
        ushort_t* Bh = Bhi + (size_t)b * B_BSTRIDE;
        ushort_t* Bl = Blo + (size_t)b * B_BSTRIDE;
#pragma unroll
        for (int q = 0; q < 8; ++q) {
            int pair = t + (q << 8);          // 0..2047
            int pw = pair & 63, cl = pair >> 6;
            if (pw < PHW) {
                int c = (chalf << 5) + cl;
                const float* row = fl + cl * 257;
                __align__(16) ushort_t h[16];
                __align__(16) ushort_t lo[16];
#pragma unroll
                for (int i = 0; i < 4; ++i)
#pragma unroll
                    for (int j = 0; j < 4; ++j) {
                        int s = min(max(pw - 1 + j, 0), 63);
                        split_bf16(row[i * 64 + s], h[i * 4 + j], lo[i * 4 + j]);
                    }
                int p = ph * PHW + pw;
                int a = frag_addr(p, c);
                *(uint4*)(Bh + a)       = *(uint4*)h;
                *(uint4*)(Bh + a + 256) = *(uint4*)(h + 8);
                *(uint4*)(Bl + a)       = *(uint4*)lo;
                *(uint4*)(Bl + a + 256) = *(uint4*)(lo + 8);
            }
        }
    }
}

// ---- kernel 4: 128x256-tile, 4-wave GEMM; A via LDS, B global->regs ------
// R17 schedule (no sleep), with COMP restructured for MFMA ILP: all 8 A-frag
// ds_reads hoisted, ONE setprio region, and the 24 MFMAs issued round-robin
// across the 8 accumulators (3 rounds of 8). Each acc still receives its 3
// updates in the original order (bh*ah, bh*al, bl*ah) -> bit-identical.
// Consecutive same-acc MFMAs are now 7 instructions apart -> dependent-chain
// latency (~4x issue) fully hidden instead of 50% exposed.
__global__ __launch_bounds__(256, 2) void gemm_kernel(
    const ushort_t* __restrict__ Ahi, const ushort_t* __restrict__ Alo,
    const ushort_t* __restrict__ Bhi, const ushort_t* __restrict__ Blo,
    float* __restrict__ Rt) {
    __shared__ ushort_t smem[2][8][512];       // [buf][seg: 0-3 Ahi rt, 4-7 Alo rt][512]
    int tid = threadIdx.x;
    int lane = tid & 63, w = tid >> 6;         // w = 0..3 (p-wave)
    int bid = blockIdx.x;                      // 0..511
    int wid = ((bid & 7) << 6) + (bid >> 3);   // bijective XCD-chunk remap
    int b = wid >> 7;
    int rem = wid & 127;
    int lg = rem >> 4;                         // 0..7  : L0 = lg*128
    int pg = rem & 15;                         // 0..15 : P0 = pg*256
    int L0 = lg << 7, P0 = pg << 8;

    // A staging sources: wave w stages segs {2w, 2w+1}
    const ushort_t* asrc[2];
#pragma unroll
    for (int i = 0; i < 2; ++i) {
        int s = 2 * w + i;
        const ushort_t* base = ((s >> 2) ? Alo : Ahi) + (size_t)b * A_BSTRIDE;
        asrc[i] = base + (size_t)((L0 >> 5) + (s & 3)) * 32768 + (size_t)(lane << 3);
    }
    ushort_t* dst0 = &smem[0][2 * w][0];
    ushort_t* dst1 = &smem[1][2 * w][0];

    // B direct-load sources: [0]=Bhi pt0, [1]=Bhi pt1, [2]=Blo pt0, [3]=Blo pt1
    const ushort_t* bsrc[4];
#pragma unroll
    for (int i = 0; i < 4; ++i) {
        const ushort_t* base = ((i >> 1) ? Blo : Bhi) + (size_t)b * B_BSTRIDE;
        bsrc[i] = base + (size_t)((P0 >> 5) + 2 * w + (i & 1)) * 32768 + (size_t)(lane << 3);
    }

#define STAGEA(dstp, kc)                                                                   \
    do {                                                                                   \
        _Pragma("unroll")                                                                  \
        for (int i = 0; i < 2; ++i)                                                        \
            __builtin_amdgcn_global_load_lds(                                              \
                (const __attribute__((address_space(1))) void*)(asrc[i] + (size_t)(kc) * 512), \
                (__attribute__((address_space(3))) void*)((dstp) + i * 512),               \
                16, 0, 0);                                                                 \
    } while (0)

#define LOADB(dst, kc)                                                    \
    do {                                                                  \
        _Pragma("unroll")                                                 \
        for (int i = 0; i < 4; ++i)                                       \
            dst[i] = *(const short8*)(bsrc[i] + (size_t)(kc) * 512);      \
    } while (0)

#define COMP(bufi, bf)                                                                     \
    do {                                                                                   \
        short8 ahf[4], alf[4];                                                             \
        _Pragma("unroll")                                                                  \
        for (int lt = 0; lt < 4; ++lt) {                                                   \
            ahf[lt] = *(const short8*)(&smem[bufi][lt][lane << 3]);                        \
            alf[lt] = *(const short8*)(&smem[bufi][4 + lt][lane << 3]);                    \
        }                                                                                  \
        __builtin_amdgcn_s_setprio(1);                                                     \
        _Pragma("unroll")                                                                  \
        for (int pt = 0; pt < 2; ++pt)                                                     \
            _Pragma("unroll")                                                              \
            for (int lt = 0; lt < 4; ++lt)                                                 \
                acc[pt][lt] = __builtin_amdgcn_mfma_f32_32x32x16_bf16(bf[pt], ahf[lt], acc[pt][lt], 0, 0, 0); \
        _Pragma("unroll")                                                                  \
        for (int pt = 0; pt < 2; ++pt)                                                     \
            _Pragma("unroll")                                                              \
            for (int lt = 0; lt < 4; ++lt)                                                 \
                acc[pt][lt] = __builtin_amdgcn_mfma_f32_32x32x16_bf16(bf[pt], alf[lt], acc[pt][lt], 0, 0, 0); \
        _Pragma("unroll")                                                                  \
        for (int pt = 0; pt < 2; ++pt)                                                     \
            _Pragma("unroll")                                                              \
            for (int lt = 0; lt < 4; ++lt)                                                 \
                acc[pt][lt] = __builtin_amdgcn_mfma_f32_32x32x16_bf16(bf[2 + pt], ahf[lt], acc[pt][lt], 0, 0, 0); \
        __builtin_amdgcn_s_setprio(0);                                                     \
    } while (0)

    floatx16 acc[2][4];
#pragma unroll
    for (int i = 0; i < 2; ++i)
#pragma unroll
        for (int j = 0; j < 4; ++j)
#pragma unroll
            for (int r = 0; r < 16; ++r) acc[i][j][r] = 0.f;

    short8 bB0[4], bB1[4];
    LOADB(bB0, 0);                             // chunk 0 B -> regs   (4 vm ops)
    STAGEA(dst0, 0);                           // chunk 0 A -> LDS    (2 vm ops)

    for (int t = 0; t < 64; t += 2) {
        // ---- even chunk t: buf0 / bB0 ----
        LOADB(bB1, t + 1);                     // next B (4)
        STAGEA(dst1, t + 1);                   // next A (2)
        asm volatile("s_waitcnt vmcnt(6)" ::: "memory");   // chunk t landed
        __builtin_amdgcn_s_barrier();
        asm volatile("" ::: "memory");
        COMP(0, bB0);
        asm volatile("" ::: "memory");
        __builtin_amdgcn_s_barrier();
        // ---- odd chunk t+1: buf1 / bB1 ----
        if (t + 2 < 64) {
            LOADB(bB0, t + 2);
            STAGEA(dst0, t + 2);
            asm volatile("s_waitcnt vmcnt(6)" ::: "memory");
        } else {
            asm volatile("s_waitcnt vmcnt(0)" ::: "memory");
        }
        __builtin_amdgcn_s_barrier();
        asm volatile("" ::: "memory");
        COMP(1, bB1);
        asm volatile("" ::: "memory");
        __builtin_amdgcn_s_barrier();
    }
#undef STAGEA
#undef LOADB
#undef COMP

    int x = lane & 31, kg = lane >> 5;
    int pw0 = P0 + (w << 6);
#pragma unroll
    for (int pt = 0; pt < 2; ++pt)
#pragma unroll
        for (int lt = 0; lt < 4; ++lt)
#pragma unroll
            for (int r = 0; r < 16; ++r) {
                int p = pw0 + (pt << 5) + (r & 3) + ((r >> 2) << 3) + (kg << 2);
                int l = L0 + (lt << 5) + x;
                if (p < NP) Rt[((size_t)b * NP + p) * NL + l] = acc[pt][lt][r];
            }
}

// ------- kernel 5: fused diag1 + diag2 + mask + softmax, row output -------
// (verified R8 per-p version: best measured non-GEMM config)
__global__ __launch_bounds__(256) void softmax_fused_kernel(const float* __restrict__ Rt,
                                                            const float* __restrict__ mmkA,
                                                            const float* __restrict__ mmpA,
                                                            float* __restrict__ E) {
    __shared__ float ld0[1024], ld1[1024], ld2[1024];
    __shared__ float red[8];
    int p = blockIdx.x, b = blockIdx.y;
    int ph = p / PHW, pw = p - ph * PHW;
    int t = threadIdx.x;
    int lane = t & 63, w = t >> 6;
    int l0 = t << 2;

    bool okm = (p != 0), okp = (p != 3968);
    int Pm = (ph > 0) ? p - 63 : 3905 + pw;
    int Pp = (ph < 62) ? p + 63 : pw + 1;

    const float* Rb = Rt + (size_t)b * NP * NL;
#define BUILD(dst, q)                                                   \
    do {                                                                \
        const float* base = Rb + (size_t)(q) * NL;                      \
        float4 r = *(const float4*)(base + l0);                         \
        if ((q) > 0) {                                                  \
            const float* pm = base - NL;                                \
            r.x += (l0 > 0) ? pm[l0 - 1] : 0.f;                         \
            r.y += pm[l0];  r.z += pm[l0 + 1];  r.w += pm[l0 + 2];      \
        }                                                               \
        if ((q) < NP - 1) {                                             \
            const float* pp = base + NL;                                \
            r.x += pp[l0 + 1];  r.y += pp[l0 + 2];  r.z += pp[l0 + 3];  \
            r.w += (l0 + 4 < NL) ? pp[l0 + 4] : 0.f;                    \
        }                                                               \
        *(float4*)(dst + l0) = r;                                       \
    } while (0)

    BUILD(ld0, p);
    if (okm) BUILD(ld1, Pm);
    if (okp) BUILD(ld2, Pp);
#undef BUILD
    __syncthreads();

    float4 vc = *(const float4*)(ld0 + l0);
    float4 vm = {0.f, 0.f, 0.f, 0.f}, vp = {0.f, 0.f, 0.f, 0.f};
    if (okm) {
        if (l0 >= 32) vm = *(const float4*)(ld1 + l0 - 32);
        else {
            vm.x = (l0 == 0) ? 0.f : ld1[l0 + 991];
            vm.y = ld1[l0 + 992];
            vm.z = ld1[l0 + 993];
            vm.w = ld1[l0 + 994];
        }
    }
    if (okp) {
        if (l0 < 992) vp = *(const float4*)(ld2 + l0 + 32);
        else {
            vp.x = ld2[l0 - 991];
            vp.y = ld2[l0 - 990];
            vp.z = ld2[l0 - 989];
            vp.w = (l0 + 3 == 1023) ? 0.f : ld2[l0 - 988];
        }
    }
    float mmpv = mmpA[b * NP + p];
    float4 km = *(const float4*)(mmkA + b * NL + l0);
    float lg[4];
    float fsum[4] = {vc.x + vm.x + vp.x, vc.y + vm.y + vp.y,
                     vc.z + vm.z + vp.z, vc.w + vm.w + vp.w};
    float kk[4] = {km.x, km.y, km.z, km.w};
#pragma unroll
    for (int i = 0; i < 4; ++i) {
        float mmv = (((kk[i] > mmpv) && (mmpv > 0.5f)) || (kk[i] == 1.0f)) ? 1.0f : 0.0f;
        lg[i] = fsum[i] * mmv * 10.0f;
    }
    float mx = fmaxf(fmaxf(lg[0], lg[1]), fmaxf(lg[2], lg[3]));
#pragma unroll
    for (int off = 32; off >= 1; off >>= 1) mx = fmaxf(mx, __shfl_xor(mx, off, 64));
    if (lane == 0) red[w] = mx;
    __syncthreads();
    mx = fmaxf(fmaxf(red[0], red[1]), fmaxf(red[2], red[3]));
    float e[4];
    float s = 0.f;
#pragma unroll
    for (int i = 0; i < 4; ++i) { e[i] = expf(lg[i] - mx); s += e[i]; }
#pragma unroll
    for (int off = 32; off >= 1; off >>= 1) s += __shfl_xor(s, off, 64);
    if (lane == 0) red[4 + w] = s;
    __syncthreads();
    float rinv = 1.0f / (red[4] + red[5] + red[6] + red[7]);
    float4 ev = {e[0] * rinv, e[1] * rinv, e[2] * rinv, e[3] * rinv};
    *(float4*)(E + (((size_t)b * NP + p) << 10) + l0) = ev;
}

// ---------------- kernel 6: tiled transpose E[p][l] -> out[l][p] ----------
__global__ __launch_bounds__(256) void transpose_kernel(const float* __restrict__ E,
                                                        float* __restrict__ out) {
    __shared__ float tile[63 * 65];
    int pt = blockIdx.x;       // 0..62 : p0 = pt*63
    int lt = blockIdx.y;       // 0..15 : l0 = lt*64
    int b  = blockIdx.z;
    int t = threadIdx.x;
    int p0 = pt * 63, l0 = lt << 6;
    const float* Eb = E + ((size_t)b * NP << 10);
    {
        int j = t & 63, i4 = t >> 6;
#pragma unroll
        for (int k = 0; k < 16; ++k) {
            int i = (k << 2) + i4;
            if (i < 63) tile[i * 65 + j] = Eb[((size_t)(p0 + i) << 10) + l0 + j];
        }
    }
    __syncthreads();
    {
        int ii = t & 63, jj4 = t >> 6;
        if (ii < 63) {
#pragma unroll
            for (int k = 0; k < 16; ++k) {
                int jj = (k << 2) + jj4;
                out[((size_t)b * NL + l0 + jj) * NP + p0 + ii] = tile[ii * 65 + jj];
            }
        }
    }
}

extern "C" void kernel_launch(void* const* d_in, const int* in_sizes, int n_in,
                              void* d_out, int out_size, void* d_ws, size_t ws_size,
                              hipStream_t stream) {
    const float* f    = (const float*)d_in[0];
    const float* b    = (const float*)d_in[1];
    const float* mask = (const float*)d_in[2];
    float* out = (float*)d_out;

    // Rt lives in d_out (consumed by softmax before transpose overwrites out).
    float* Rt = (float*)d_out;

    // ws layout (floats): E at [16257024 .. 32514048); stats after.
    // A'/B' (~84 MB) occupy ws from 0 but are dead post-GEMM.
    float* wsf = (float*)d_ws;
    float* E  = wsf + 16257024;
    ushort_t* Ahi = (ushort_t*)d_ws;
    ushort_t* Alo = Ahi + (size_t)NB * A_BSTRIDE;
    ushort_t* Bhi = Alo + (size_t)NB * A_BSTRIDE;
    ushort_t* Blo = Bhi + (size_t)NB * B_BSTRIDE;
    float* invn = wsf + 32514048;
    float* mmk = invn + 256;
    float* mmp = mmk + 4096;

    prep_kernel<<<dim3(847), dim3(256), 0, stream>>>(b, mask, invn, mmk, mmp, Bhi, Blo);
    split_kernel<<<dim3(95, 4, 2), dim3(256), 0, stream>>>(b, invn, Ahi, Alo, f, Bhi, Blo);
    gemm_kernel<<<dim3(512), dim3(256), 0, stream>>>(Ahi, Alo, Bhi, Blo, Rt);
    softmax_fused_kernel<<<dim3(3969, 4), dim3(256), 0, stream>>>(Rt, mmk, mmp, E);
    transpose_kernel<<<dim3(63, 16, 4), dim3(256), 0, stream>>>(E, out);
}

// Round 21
// 263.097 us; speedup vs baseline: 1.0010x; 1.0003x over previous
//
#include <hip/hip_runtime.h>
#include <math.h>

#define NB 4
#define NC 64
#define NL 1024   // 32x32 kernel-patch grid
#define NP 3969   // 63x63 correlation positions
#define PHW 63

typedef unsigned short ushort_t;
typedef __attribute__((ext_vector_type(8))) short short8;
typedef __attribute__((ext_vector_type(16))) float floatx16;

// A' per b: 32 rtiles * 64 kchunks * 64 lanes * 8 = 2^20 ushorts
#define A_BSTRIDE 1048576
// B' per b: 128 rtiles (4096 rows, padded for 256-wide p-tiles) * 64 * 512
#define B_BSTRIDE 4194304

// ---------------- kernel 1: fused prep = norm + stats + padB --------------
__global__ __launch_bounds__(256) void prep_kernel(const float* __restrict__ bsrc,
                                                   const float* __restrict__ mask,
                                                   float* __restrict__ invn,
                                                   float* __restrict__ mmk,
                                                   float* __restrict__ mmp,
                                                   ushort_t* __restrict__ Bhi,
                                                   ushort_t* __restrict__ Blo) {
    int blk = blockIdx.x;
    if (blk < 256) {
        const float* src = bsrc + (size_t)blk * 4096;
        float s = 0.f;
        for (int i = threadIdx.x; i < 4096; i += 256) { float v = src[i]; s += v * v; }
#pragma unroll
        for (int off = 32; off > 0; off >>= 1) s += __shfl_down(s, off, 64);
        __shared__ float part[4];
        if ((threadIdx.x & 63) == 0) part[threadIdx.x >> 6] = s;
        __syncthreads();
        if (threadIdx.x == 0) {
            float t = part[0] + part[1] + part[2] + part[3];
            invn[blk] = 1.0f / sqrtf(t + 1e-8f);
        }
    } else if (blk < 335) {
        int id = (blk - 256) * 256 + threadIdx.x;
        if (id < NB * NL) {
            int b = id >> 10, l = id & 1023;
            int lh = l >> 5, lw = l & 31;
            const float* m = mask + b * 4096;
            float s = 0.f;
#pragma unroll
            for (int i = 0; i < 4; ++i) {
                int r = min(max(2 * lh - 1 + i, 0), 63);
#pragma unroll
                for (int j = 0; j < 4; ++j) {
                    int c = min(max(2 * lw - 1 + j, 0), 63);
                    s += 1.0f - m[r * 64 + c];
                }
            }
            mmk[id] = s * (1.0f / 16.0f);
        } else {
            int id2 = id - NB * NL;
            if (id2 < NB * NP) {
                int b = id2 / NP, p = id2 - b * NP;
                int ph = p / PHW, pw = p - ph * PHW;
                const float* m = mask + b * 4096;
                float s = 0.f;
#pragma unroll
                for (int i = 0; i < 4; ++i) {
                    int r = min(max(ph - 1 + i, 0), 63);
#pragma unroll
                    for (int j = 0; j < 4; ++j) {
                        int c = min(max(pw - 1 + j, 0), 63);
                        s += 1.0f - m[r * 64 + c];
                    }
                }
                mmp[id2] = s * (1.0f / 16.0f);
            }
        }
    } else {
        // zero rtiles 124..127 (rows 3968..4095) for all b, both matrices
        int idx = (blk - 335) * 256 + threadIdx.x;   // 0..131071
        int b = idx >> 15;
        int r = idx & 32767;
        int mat = r >> 14;
        int o = r & 16383;
        ushort_t* base = (mat ? Blo : Bhi) + (size_t)b * B_BSTRIDE + 124 * 32768;
        uint4 z = {0u, 0u, 0u, 0u};
        ((uint4*)base)[o] = z;
    }
}

// ------------- split helper: fp32 -> bf16 hi + bf16 residual --------------
__device__ inline void split_bf16(float v, ushort_t& hv, ushort_t& lv) {
    unsigned u = __float_as_uint(v);
    unsigned rr = u + 0x7FFFu + ((u >> 16) & 1u);
    hv = (ushort_t)(rr >> 16);
    float fh = __uint_as_float(((unsigned)hv) << 16);
    float remv = v - fh;
    unsigned u2 = __float_as_uint(remv);
    unsigned rr2 = u2 + 0x7FFFu + ((u2 >> 16) & 1u);
    lv = (ushort_t)(rr2 >> 16);
}

// fragment-order address for (row, kchunk)
__device__ inline int frag_addr(int row, int kc) {
    return ((row >> 5) * 64 + kc) * 512 + (row & 31) * 8;
}

// --------- kernel 3: merged splitA (x<32) + splitB (x>=32) ---------------
__global__ __launch_bounds__(256) void split_kernel(const float* __restrict__ bsrc,
                                                    const float* __restrict__ invn,
                                                    ushort_t* __restrict__ Ahi,
                                                    ushort_t* __restrict__ Alo,
                                                    const float* __restrict__ fsrc,
                                                    ushort_t* __restrict__ Bhi,
                                                    ushort_t* __restrict__ Blo) {
    __shared__ float fl[32 * 257];
    int x = blockIdx.x, b = blockIdx.y, chalf = blockIdx.z;
    int t = threadIdx.x;
    if (x < 32) {
        int lh = x;
#pragma unroll
        for (int q = 0; q < 32; ++q) {
            int idx = t + (q << 8);
            int cl = idx >> 8, rem = idx & 255;
            int i = rem >> 6, s = rem & 63;
            int c = (chalf << 5) + cl;
            int r = min(max(2 * lh - 1 + i, 0), 63);
            fl[cl * 257 + rem] = bsrc[(((size_t)((b << 6) + c)) << 12) + (r << 6) + s];
        }
        __syncthreads();
        ushort_t* Ah = Ahi + (size_t)b * A_BSTRIDE;
        ushort_t* Al = Alo + (size_t)b * A_BSTRIDE;
#pragma unroll
        for (int q = 0; q < 4; ++q) {
            int pair = t + (q << 8);         // 0..1023
            int lw = pair & 31, cl = pair >> 5;
            int c = (chalf << 5) + cl;
            float scale = invn[(b << 6) + c];
            const float* row = fl + cl * 257;
            __align__(16) ushort_t h[16];
            __align__(16) ushort_t lo[16];
#pragma unroll
            for (int i = 0; i < 4; ++i)
#pragma unroll
                for (int j = 0; j < 4; ++j) {
                    int s = min(max(2 * lw - 1 + j, 0), 63);
                    split_bf16(row[i * 64 + s] * scale, h[i * 4 + j], lo[i * 4 + j]);
                }
            int a = (lh * 64 + c) * 512 + lw * 8;
            *(uint4*)(Ah + a)       = *(uint4*)h;
            *(uint4*)(Ah + a + 256) = *(uint4*)(h + 8);
            *(uint4*)(Al + a)       = *(uint4*)lo;
            *(uint4*)(Al + a + 256) = *(uint4*)(lo + 8);
        }
    } else {
        int ph = x - 32;
#pragma unroll
        for (int q = 0; q < 32; ++q) {
            int idx = t + (q << 8);
            int cl = idx >> 8, rem = idx & 255;
            int i = rem >> 6, s = rem & 63;
            int c = (chalf << 5) + cl;
            int r = min(max(ph - 1 + i, 0), 63);
            fl[cl * 257 + rem] = fsrc[(((size_t)((b << 6) + c)) << 12) + (r << 6) + s];
        }
        __syncthreads();
        ushort_t* Bh = Bhi + (size_t)b * B_BSTRIDE;
        ushort_t* Bl = Blo + (size_t)b * B_BSTRIDE;
#pragma unroll
        for (int q = 0; q < 8; ++q) {
            int pair = t + (q << 8);          // 0..2047
            int pw = pair & 63, cl = pair >> 6;
            if (pw < PHW) {
                int c = (chalf << 5) + cl;
                const float* row = fl + cl * 257;
                __align__(16) ushort_t h[16];
                __align__(16) ushort_t lo[16];
#pragma unroll
                for (int i = 0; i < 4; ++i)
#pragma unroll
                    for (int j = 0; j < 4; ++j) {
                        int s = min(max(pw - 1 + j, 0), 63);
                        split_bf16(row[i * 64 + s], h[i * 4 + j], lo[i * 4 + j]);
                    }
                int p = ph * PHW + pw;
                int a = frag_addr(p, c);
                *(uint4*)(Bh + a)       = *(uint4*)h;
                *(uint4*)(Bh + a + 256) = *(uint4*)(h + 8);
                *(uint4*)(Bl + a)       = *(uint4*)lo;
                *(uint4*)(Bl + a + 256) = *(uint4*)(lo + 8);
            }
        }
    }
}

// ---- kernel 4: 128x256 GEMM; A group-staged (4 chunks/barrier), B regs ---
// Barrier amortization: A staged in groups of 4 K-chunks (8 gload_lds/wave/
// group into 2x 32KB LDS bufs), ONE barrier per group (16 total vs 128).
// Per chunk only a counted vmcnt(12) retires that chunk's 4 B-loads while
// the group's 8 A-loads stay in flight; vmcnt(4) drains A at group end.
// MFMA values/order per accumulator unchanged -> bit-identical numerics.
__global__ __launch_bounds__(256, 2) void gemm_kernel(
    const ushort_t* __restrict__ Ahi, const ushort_t* __restrict__ Alo,
    const ushort_t* __restrict__ Bhi, const ushort_t* __restrict__ Blo,
    float* __restrict__ Rt) {
    __shared__ ushort_t smem[2][4][8][512];    // [buf][chunk-in-group][seg][512] = 64 KB
    int tid = threadIdx.x;
    int lane = tid & 63, w = tid >> 6;         // w = 0..3 (p-wave)
    int bid = blockIdx.x;                      // 0..511
    int wid = ((bid & 7) << 6) + (bid >> 3);   // bijective XCD-chunk remap
    int b = wid >> 7;
    int rem = wid & 127;
    int lg = rem >> 4;                         // 0..7  : L0 = lg*128
    int pg = rem & 15;                         // 0..15 : P0 = pg*256
    int L0 = lg << 7, P0 = pg << 8;

    // A staging sources: wave w stages segs {2w, 2w+1}
    const ushort_t* asrc[2];
#pragma unroll
    for (int i = 0; i < 2; ++i) {
        int s = 2 * w + i;
        const ushort_t* base = ((s >> 2) ? Alo : Ahi) + (size_t)b * A_BSTRIDE;
        asrc[i] = base + (size_t)((L0 >> 5) + (s & 3)) * 32768 + (size_t)(lane << 3);
    }

    // B direct-load sources: [0]=Bhi pt0, [1]=Bhi pt1, [2]=Blo pt0, [3]=Blo pt1
    const ushort_t* bsrc[4];
#pragma unroll
    for (int i = 0; i < 4; ++i) {
        const ushort_t* base = ((i >> 1) ? Blo : Bhi) + (size_t)b * B_BSTRIDE;
        bsrc[i] = base + (size_t)((P0 >> 5) + 2 * w + (i & 1)) * 32768 + (size_t)(lane << 3);
    }

// stage 4 chunks (group g) of A into smem[bufi][0..3][2w,2w+1] : 8 vm ops
#define STAGEA_G(bufi, g)                                                                  \
    do {                                                                                   \
        _Pragma("unroll")                                                                  \
        for (int c = 0; c < 4; ++c)                                                        \
            _Pragma("unroll")                                                              \
            for (int i = 0; i < 2; ++i)                                                    \
                __builtin_amdgcn_global_load_lds(                                          \
                    (const __attribute__((address_space(1))) void*)(asrc[i] + (size_t)(4 * (g) + c) * 512), \
                    (__attribute__((address_space(3))) void*)(&smem[bufi][c][2 * w + i][0]), \
                    16, 0, 0);                                                             \
    } while (0)

#define LOADB(dst, kc)                                                    \
    do {                                                                  \
        int kcc = min((kc), 63);                                          \
        _Pragma("unroll")                                                 \
        for (int i = 0; i < 4; ++i)                                       \
            dst[i] = *(const short8*)(bsrc[i] + (size_t)kcc * 512);       \
    } while (0)

#define COMP(bufi, c, bf)                                                                  \
    do {                                                                                   \
        short8 ahf[4], alf[4];                                                             \
        _Pragma("unroll")                                                                  \
        for (int lt = 0; lt < 4; ++lt) {                                                   \
            ahf[lt] = *(const short8*)(&smem[bufi][c][lt][lane << 3]);                     \
            alf[lt] = *(const short8*)(&smem[bufi][c][4 + lt][lane << 3]);                 \
        }                                                                                  \
        __builtin_amdgcn_s_setprio(1);                                                     \
        _Pragma("unroll")                                                                  \
        for (int pt = 0; pt < 2; ++pt)                                                     \
            _Pragma("unroll")                                                              \
            for (int lt = 0; lt < 4; ++lt)                                                 \
                acc[pt][lt] = __builtin_amdgcn_mfma_f32_32x32x16_bf16(bf[pt], ahf[lt], acc[pt][lt], 0, 0, 0); \
        _Pragma("unroll")                                                                  \
        for (int pt = 0; pt < 2; ++pt)                                                     \
            _Pragma("unroll")                                                              \
            for (int lt = 0; lt < 4; ++lt)                                                 \
                acc[pt][lt] = __builtin_amdgcn_mfma_f32_32x32x16_bf16(bf[pt], alf[lt], acc[pt][lt], 0, 0, 0); \
        _Pragma("unroll")                                                                  \
        for (int pt = 0; pt < 2; ++pt)                                                     \
            _Pragma("unroll")                                                              \
            for (int lt = 0; lt < 4; ++lt)                                                 \
                acc[pt][lt] = __builtin_amdgcn_mfma_f32_32x32x16_bf16(bf[2 + pt], ahf[lt], acc[pt][lt], 0, 0, 0); \
        __builtin_amdgcn_s_setprio(0);                                                     \
    } while (0)

// counted wait: B for current chunk done; group A8 + next B4 stay in flight
#define WAIT_B_MID()  asm volatile("s_waitcnt vmcnt(12)" ::: "memory")
// last group (no A in flight): outstanding = Bcur4 + Bnext4
#define WAIT_B_LAST() asm volatile("s_waitcnt vmcnt(4)" ::: "memory")

    floatx16 acc[2][4];
#pragma unroll
    for (int i = 0; i < 2; ++i)
#pragma unroll
        for (int j = 0; j < 4; ++j)
#pragma unroll
            for (int r = 0; r < 16; ++r) acc[i][j][r] = 0.f;

    short8 bA[4], bBb[4];

    // prologue: group 0 A + chunk 0 B
    STAGEA_G(0, 0);                            // 8 ops
    LOADB(bA, 0);                              // 4 ops
    asm volatile("s_waitcnt vmcnt(4)" ::: "memory");   // A(g0) landed
    __builtin_amdgcn_s_barrier();
    asm volatile("" ::: "memory");

    for (int g = 0; g < 16; ++g) {
        int bufi = g & 1;
        bool notlast = (g + 1 < 16);
        // c0: issue next group's A + next B, wait current B, compute
        if (notlast) STAGEA_G(bufi ^ 1, g + 1);          // 8 ops
        LOADB(bBb, 4 * g + 1);                            // 4 ops
        if (notlast) WAIT_B_MID(); else WAIT_B_LAST();
        COMP(bufi, 0, bA);
        // c1
        LOADB(bA, 4 * g + 2);
        if (notlast) WAIT_B_MID(); else WAIT_B_LAST();
        COMP(bufi, 1, bBb);
        // c2
        LOADB(bBb, 4 * g + 3);
        if (notlast) WAIT_B_MID(); else WAIT_B_LAST();
        COMP(bufi, 2, bA);
        // c3
        LOADB(bA, 4 * g + 4);
        if (notlast) WAIT_B_MID(); else WAIT_B_LAST();
        COMP(bufi, 3, bBb);
        // group end: publish next group's A (skip after final group)
        if (notlast) {
            asm volatile("s_waitcnt vmcnt(4)" ::: "memory");   // A(g+1) landed
            __builtin_amdgcn_s_barrier();
            asm volatile("" ::: "memory");
        }
    }
#undef STAGEA_G
#undef LOADB
#undef COMP
#undef WAIT_B_MID
#undef WAIT_B_LAST

    int x = lane & 31, kg = lane >> 5;
    int pw0 = P0 + (w << 6);
#pragma unroll
    for (int pt = 0; pt < 2; ++pt)
#pragma unroll
        for (int lt = 0; lt < 4; ++lt)
#pragma unroll
            for (int r = 0; r < 16; ++r) {
                int p = pw0 + (pt << 5) + (r & 3) + ((r >> 2) << 3) + (kg << 2);
                int l = L0 + (lt << 5) + x;
                if (p < NP) Rt[((size_t)b * NP + p) * NL + l] = acc[pt][lt][r];
            }
}

// ------- kernel 5: fused diag1 + diag2 + mask + softmax, row output -------
// (verified R8 per-p version: best measured non-GEMM config)
__global__ __launch_bounds__(256) void softmax_fused_kernel(const float* __restrict__ Rt,
                                                            const float* __restrict__ mmkA,
                                                            const float* __restrict__ mmpA,
                                                            float* __restrict__ E) {
    __shared__ float ld0[1024], ld1[1024], ld2[1024];
    __shared__ float red[8];
    int p = blockIdx.x, b = blockIdx.y;
    int ph = p / PHW, pw = p - ph * PHW;
    int t = threadIdx.x;
    int lane = t & 63, w = t >> 6;
    int l0 = t << 2;

    bool okm = (p != 0), okp = (p != 3968);
    int Pm = (ph > 0) ? p - 63 : 3905 + pw;
    int Pp = (ph < 62) ? p + 63 : pw + 1;

    const float* Rb = Rt + (size_t)b * NP * NL;
#define BUILD(dst, q)                                                   \
    do {                                                                \
        const float* base = Rb + (size_t)(q) * NL;                      \
        float4 r = *(const float4*)(base + l0);                         \
        if ((q) > 0) {                                                  \
            const float* pm = base - NL;                                \
            r.x += (l0 > 0) ? pm[l0 - 1] : 0.f;                         \
            r.y += pm[l0];  r.z += pm[l0 + 1];  r.w += pm[l0 + 2];      \
        }                                                               \
        if ((q) < NP - 1) {                                             \
            const float* pp = base + NL;                                \
            r.x += pp[l0 + 1];  r.y += pp[l0 + 2];  r.z += pp[l0 + 3];  \
            r.w += (l0 + 4 < NL) ? pp[l0 + 4] : 0.f;                    \
        }                                                               \
        *(float4*)(dst + l0) = r;                                       \
    } while (0)

    BUILD(ld0, p);
    if (okm) BUILD(ld1, Pm);
    if (okp) BUILD(ld2, Pp);
#undef BUILD
    __syncthreads();

    float4 vc = *(const float4*)(ld0 + l0);
    float4 vm = {0.f, 0.f, 0.f, 0.f}, vp = {0.f, 0.f, 0.f, 0.f};
    if (okm) {
        if (l0 >= 32) vm = *(const float4*)(ld1 + l0 - 32);
        else {
            vm.x = (l0 == 0) ? 0.f : ld1[l0 + 991];
            vm.y = ld1[l0 + 992];
            vm.z = ld1[l0 + 993];
            vm.w = ld1[l0 + 994];
        }
    }
    if (okp) {
        if (l0 < 992) vp = *(const float4*)(ld2 + l0 + 32);
        else {
            vp.x = ld2[l0 - 991];
            vp.y = ld2[l0 - 990];
            vp.z = ld2[l0 - 989];
            vp.w = (l0 + 3 == 1023) ? 0.f : ld2[l0 - 988];
        }
    }
    float mmpv = mmpA[b * NP + p];
    float4 km = *(const float4*)(mmkA + b * NL + l0);
    float lg[4];
    float fsum[4] = {vc.x + vm.x + vp.x, vc.y + vm.y + vp.y,
                     vc.z + vm.z + vp.z, vc.w + vm.w + vp.w};
    float kk[4] = {km.x, km.y, km.z, km.w};
#pragma unroll
    for (int i = 0; i < 4; ++i) {
        float mmv = (((kk[i] > mmpv) && (mmpv > 0.5f)) || (kk[i] == 1.0f)) ? 1.0f : 0.0f;
        lg[i] = fsum[i] * mmv * 10.0f;
    }
    float mx = fmaxf(fmaxf(lg[0], lg[1]), fmaxf(lg[2], lg[3]));
#pragma unroll
    for (int off = 32; off >= 1; off >>= 1) mx = fmaxf(mx, __shfl_xor(mx, off, 64));
    if (lane == 0) red[w] = mx;
    __syncthreads();
    mx = fmaxf(fmaxf(red[0], red[1]), fmaxf(red[2], red[3]));
    float e[4];
    float s = 0.f;
#pragma unroll
    for (int i = 0; i < 4; ++i) { e[i] = expf(lg[i] - mx); s += e[i]; }
#pragma unroll
    for (int off = 32; off >= 1; off >>= 1) s += __shfl_xor(s, off, 64);
    if (lane == 0) red[4 + w] = s;
    __syncthreads();
    float rinv = 1.0f / (red[4] + red[5] + red[6] + red[7]);
    float4 ev = {e[0] * rinv, e[1] * rinv, e[2] * rinv, e[3] * rinv};
    *(float4*)(E + (((size_t)b * NP + p) << 10) + l0) = ev;
}

// ---------------- kernel 6: tiled transpose E[p][l] -> out[l][p] ----------
__global__ __launch_bounds__(256) void transpose_kernel(const float* __restrict__ E,
                                                        float* __restrict__ out) {
    __shared__ float tile[63 * 65];
    int pt = blockIdx.x;       // 0..62 : p0 = pt*63
    int lt = blockIdx.y;       // 0..15 : l0 = lt*64
    int b  = blockIdx.z;
    int t = threadIdx.x;
    int p0 = pt * 63, l0 = lt << 6;
    const float* Eb = E + ((size_t)b * NP << 10);
    {
        int j = t & 63, i4 = t >> 6;
#pragma unroll
        for (int k = 0; k < 16; ++k) {
            int i = (k << 2) + i4;
            if (i < 63) tile[i * 65 + j] = Eb[((size_t)(p0 + i) << 10) + l0 + j];
        }
    }
    __syncthreads();
    {
        int ii = t & 63, jj4 = t >> 6;
        if (ii < 63) {
#pragma unroll
            for (int k = 0; k < 16; ++k) {
                int jj = (k << 2) + jj4;
                out[((size_t)b * NL + l0 + jj) * NP + p0 + ii] = tile[ii * 65 + jj];
            }
        }
    }
}

extern "C" void kernel_launch(void* const* d_in, const int* in_sizes, int n_in,
                              void* d_out, int out_size, void* d_ws, size_t ws_size,
                              hipStream_t stream) {
    const float* f    = (const float*)d_in[0];
    const float* b    = (const float*)d_in[1];
    const float* mask = (const float*)d_in[2];
    float* out = (float*)d_out;

    // Rt lives in d_out (consumed by softmax before transpose overwrites out).
    float* Rt = (float*)d_out;

    // ws layout (floats): E at [16257024 .. 32514048); stats after.
    // A'/B' (~84 MB) occupy ws from 0 but are dead post-GEMM.
    float* wsf = (float*)d_ws;
    float* E  = wsf + 16257024;
    ushort_t* Ahi = (ushort_t*)d_ws;
    ushort_t* Alo = Ahi + (size_t)NB * A_BSTRIDE;
    ushort_t* Bhi = Alo + (size_t)NB * A_BSTRIDE;
    ushort_t* Blo = Bhi + (size_t)NB * B_BSTRIDE;
    float* invn = wsf + 32514048;
    float* mmk = invn + 256;
    float* mmp = mmk + 4096;

    prep_kernel<<<dim3(847), dim3(256), 0, stream>>>(b, mask, invn, mmk, mmp, Bhi, Blo);
    split_kernel<<<dim3(95, 4, 2), dim3(256), 0, stream>>>(b, invn, Ahi, Alo, f, Bhi, Blo);
    gemm_kernel<<<dim3(512), dim3(256), 0, stream>>>(Ahi, Alo, Bhi, Blo, Rt);
    softmax_fused_kernel<<<dim3(3969, 4), dim3(256), 0, stream>>>(Rt, mmk, mmp, E);
    transpose_kernel<<<dim3(63, 16, 4), dim3(256), 0, stream>>>(E, out);
}

// Round 22
// 260.724 us; speedup vs baseline: 1.0101x; 1.0091x over previous
//
#include <hip/hip_runtime.h>
#include <math.h>

#define NB 4
#define NC 64
#define NL 1024   // 32x32 kernel-patch grid
#define NP 3969   // 63x63 correlation positions
#define PHW 63

typedef unsigned short ushort_t;
typedef __attribute__((ext_vector_type(8))) short short8;
typedef __attribute__((ext_vector_type(16))) float floatx16;

// A' per b: 32 rtiles * 64 kchunks * 64 lanes * 8 = 2^20 ushorts
#define A_BSTRIDE 1048576
// B' per b: 128 rtiles (4096 rows, padded for 256-wide p-tiles) * 64 * 512
#define B_BSTRIDE 4194304

// ---------------- kernel 1: fused prep = norm + stats + padB --------------
__global__ __launch_bounds__(256) void prep_kernel(const float* __restrict__ bsrc,
                                                   const float* __restrict__ mask,
                                                   float* __restrict__ invn,
                                                   float* __restrict__ mmk,
                                                   float* __restrict__ mmp,
                                                   ushort_t* __restrict__ Bhi,
                                                   ushort_t* __restrict__ Blo) {
    int blk = blockIdx.x;
    if (blk < 256) {
        const float* src = bsrc + (size_t)blk * 4096;
        float s = 0.f;
        for (int i = threadIdx.x; i < 4096; i += 256) { float v = src[i]; s += v * v; }
#pragma unroll
        for (int off = 32; off > 0; off >>= 1) s += __shfl_down(s, off, 64);
        __shared__ float part[4];
        if ((threadIdx.x & 63) == 0) part[threadIdx.x >> 6] = s;
        __syncthreads();
        if (threadIdx.x == 0) {
            float t = part[0] + part[1] + part[2] + part[3];
            invn[blk] = 1.0f / sqrtf(t + 1e-8f);
        }
    } else if (blk < 335) {
        int id = (blk - 256) * 256 + threadIdx.x;
        if (id < NB * NL) {
            int b = id >> 10, l = id & 1023;
            int lh = l >> 5, lw = l & 31;
            const float* m = mask + b * 4096;
            float s = 0.f;
#pragma unroll
            for (int i = 0; i < 4; ++i) {
                int r = min(max(2 * lh - 1 + i, 0), 63);
#pragma unroll
                for (int j = 0; j < 4; ++j) {
                    int c = min(max(2 * lw - 1 + j, 0), 63);
                    s += 1.0f - m[r * 64 + c];
                }
            }
            mmk[id] = s * (1.0f / 16.0f);
        } else {
            int id2 = id - NB * NL;
            if (id2 < NB * NP) {
                int b = id2 / NP, p = id2 - b * NP;
                int ph = p / PHW, pw = p - ph * PHW;
                const float* m = mask + b * 4096;
                float s = 0.f;
#pragma unroll
                for (int i = 0; i < 4; ++i) {
                    int r = min(max(ph - 1 + i, 0), 63);
#pragma unroll
                    for (int j = 0; j < 4; ++j) {
                        int c = min(max(pw - 1 + j, 0), 63);
                        s += 1.0f - m[r * 64 + c];
                    }
                }
                mmp[id2] = s * (1.0f / 16.0f);
            }
        }
    } else {
        // zero rtiles 124..127 (rows 3968..4095) for all b, both matrices
        int idx = (blk - 335) * 256 + threadIdx.x;   // 0..131071
        int b = idx >> 15;
        int r = idx & 32767;
        int mat = r >> 14;
        int o = r & 16383;
        ushort_t* base = (mat ? Blo : Bhi) + (size_t)b * B_BSTRIDE + 124 * 32768;
        uint4 z = {0u, 0u, 0u, 0u};
        ((uint4*)base)[o] = z;
    }
}

// ------------- split helper: fp32 -> bf16 hi + bf16 residual --------------
__device__ inline void split_bf16(float v, ushort_t& hv, ushort_t& lv) {
    unsigned u = __float_as_uint(v);
    unsigned rr = u + 0x7FFFu + ((u >> 16) & 1u);
    hv = (ushort_t)(rr >> 16);
    float fh = __uint_as_float(((unsigned)hv) << 16);
    float remv = v - fh;
    unsigned u2 = __float_as_uint(remv);
    unsigned rr2 = u2 + 0x7FFFu + ((u2 >> 16) & 1u);
    lv = (ushort_t)(rr2 >> 16);
}

// fragment-order address for (row, kchunk)
__device__ inline int frag_addr(int row, int kc) {
    return ((row >> 5) * 64 + kc) * 512 + (row & 31) * 8;
}

// --------- kernel 3: merged splitA (x<32) + splitB (x>=32) ---------------
__global__ __launch_bounds__(256) void split_kernel(const float* __restrict__ bsrc,
                                                    const float* __restrict__ invn,
                                                    ushort_t* __restrict__ Ahi,
                                                    ushort_t* __restrict__ Alo,
                                                    const float* __restrict__ fsrc,
                                                    ushort_t* __restrict__ Bhi,
                                                    ushort_t* __restrict__ Blo) {
    __shared__ float fl[32 * 257];
    int x = blockIdx.x, b = blockIdx.y, chalf = blockIdx.z;
    int t = threadIdx.x;
    if (x < 32) {
        int lh = x;
#pragma unroll
        for (int q = 0; q < 32; ++q) {
            int idx = t + (q << 8);
            int cl = idx >> 8, rem = idx & 255;
            int i = rem >> 6, s = rem & 63;
            int c = (chalf << 5) + cl;
            int r = min(max(2 * lh - 1 + i, 0), 63);
            fl[cl * 257 + rem] = bsrc[(((size_t)((b << 6) + c)) << 12) + (r << 6) + s];
        }
        __syncthreads();
        ushort_t* Ah = Ahi + (size_t)b * A_BSTRIDE;
        ushort_t* Al = Alo + (size_t)b * A_BSTRIDE;
#pragma unroll
        for (int q = 0; q < 4; ++q) {
            int pair = t + (q << 8);         // 0..1023
            int lw = pair & 31, cl = pair >> 5;
            int c = (chalf << 5) + cl;
            float scale = invn[(b << 6) + c];
            const float* row = fl + cl * 257;
            __align__(16) ushort_t h[16];
            __align__(16) ushort_t lo[16];
#pragma unroll
            for (int i = 0; i < 4; ++i)
#pragma unroll
                for (int j = 0; j < 4; ++j) {
                    int s = min(max(2 * lw - 1 + j, 0), 63);
                    split_bf16(row[i * 64 + s] * scale, h[i * 4 + j], lo[i * 4 + j]);
                }
            int a = (lh * 64 + c) * 512 + lw * 8;
            *(uint4*)(Ah + a)       = *(uint4*)h;
            *(uint4*)(Ah + a + 256) = *(uint4*)(h + 8);
            *(uint4*)(Al + a)       = *(uint4*)lo;
            *(uint4*)(Al + a + 256) = *(uint4*)(lo + 8);
        }
    } else {
        int ph = x - 32;
#pragma unroll
        for (int q = 0; q < 32; ++q) {
            int idx = t + (q << 8);
            int cl = idx >> 8, rem = idx & 255;
            int i = rem >> 6, s = rem & 63;
            int c = (chalf << 5) + cl;
            int r = min(max(ph - 1 + i, 0), 63);
            fl[cl * 257 + rem] = fsrc[(((size_t)((b << 6) + c)) << 12) + (r << 6) + s];
        }
        __syncthreads();
        ushort_t* Bh = Bhi + (size_t)b * B_BSTRIDE;
        ushort_t* Bl = Blo + (size_t)b * B_BSTRIDE;
#pragma unroll
        for (int q = 0; q < 8; ++q) {
            int pair = t + (q << 8);          // 0..2047
            int pw = pair & 63, cl = pair >> 6;
            if (pw < PHW) {
                int c = (chalf << 5) + cl;
                const float* row = fl + cl * 257;
                __align__(16) ushort_t h[16];
                __align__(16) ushort_t lo[16];
#pragma unroll
                for (int i = 0; i < 4; ++i)
#pragma unroll
                    for (int j = 0; j < 4; ++j) {
                        int s = min(max(pw - 1 + j, 0), 63);
                        split_bf16(row[i * 64 + s], h[i * 4 + j], lo[i * 4 + j]);
                    }
                int p = ph * PHW + pw;
                int a = frag_addr(p, c);
                *(uint4*)(Bh + a)       = *(uint4*)h;
                *(uint4*)(Bh + a + 256) = *(uint4*)(h + 8);
                *(uint4*)(Bl + a)       = *(uint4*)lo;
                *(uint4*)(Bl + a + 256) = *(uint4*)(lo + 8);
            }
        }
    }
}

// ---- kernel 4: 128x256-tile, 4-wave GEMM; A via LDS, B global->regs ------
// Best measured configuration (R17: gemm 88.7 us, MfmaUtil 51%). B fragments
// are wave-private so they skip LDS (4 dwordx4/chunk, register-dbuf one
// chunk ahead); A (shared by 4 waves) LDS-staged 16 KB dbuf. vmcnt(6)
// counted (T4), raw barriers, setprio (T5), XCD swizzle (T1).
// 2-phase family plateau: 5 schedule variants (operand-stream, cross-block
// TLP, LDS-BW, de-phase, MFMA-ILP, barrier-amortize) all measured null at
// MfmaUtil 50+-2% -> residual gap is the aggregate 2-phase sync structure
// (m233); next lever would be a full 8-phase co-designed port.
__global__ __launch_bounds__(256, 2) void gemm_kernel(
    const ushort_t* __restrict__ Ahi, const ushort_t* __restrict__ Alo,
    const ushort_t* __restrict__ Bhi, const ushort_t* __restrict__ Blo,
    float* __restrict__ Rt) {
    __shared__ ushort_t smem[2][8][512];       // [buf][seg: 0-3 Ahi rt, 4-7 Alo rt][512]
    int tid = threadIdx.x;
    int lane = tid & 63, w = tid >> 6;         // w = 0..3 (p-wave)
    int bid = blockIdx.x;                      // 0..511
    int wid = ((bid & 7) << 6) + (bid >> 3);   // bijective XCD-chunk remap
    int b = wid >> 7;
    int rem = wid & 127;
    int lg = rem >> 4;                         // 0..7  : L0 = lg*128
    int pg = rem & 15;                         // 0..15 : P0 = pg*256
    int L0 = lg << 7, P0 = pg << 8;

    // A staging sources: wave w stages segs {2w, 2w+1}
    const ushort_t* asrc[2];
#pragma unroll
    for (int i = 0; i < 2; ++i) {
        int s = 2 * w + i;
        const ushort_t* base = ((s >> 2) ? Alo : Ahi) + (size_t)b * A_BSTRIDE;
        asrc[i] = base + (size_t)((L0 >> 5) + (s & 3)) * 32768 + (size_t)(lane << 3);
    }
    ushort_t* dst0 = &smem[0][2 * w][0];
    ushort_t* dst1 = &smem[1][2 * w][0];

    // B direct-load sources: [0]=Bhi pt0, [1]=Bhi pt1, [2]=Blo pt0, [3]=Blo pt1
    const ushort_t* bsrc[4];
#pragma unroll
    for (int i = 0; i < 4; ++i) {
        const ushort_t* base = ((i >> 1) ? Blo : Bhi) + (size_t)b * B_BSTRIDE;
        bsrc[i] = base + (size_t)((P0 >> 5) + 2 * w + (i & 1)) * 32768 + (size_t)(lane << 3);
    }

#define STAGEA(dstp, kc)                                                                   \
    do {                                                                                   \
        _Pragma("unroll")                                                                  \
        for (int i = 0; i < 2; ++i)                                                        \
            __builtin_amdgcn_global_load_lds(                                              \
                (const __attribute__((address_space(1))) void*)(asrc[i] + (size_t)(kc) * 512), \
                (__attribute__((address_space(3))) void*)((dstp) + i * 512),               \
                16, 0, 0);                                                                 \
    } while (0)

#define LOADB(dst, kc)                                                    \
    do {                                                                  \
        _Pragma("unroll")                                                 \
        for (int i = 0; i < 4; ++i)                                       \
            dst[i] = *(const short8*)(bsrc[i] + (size_t)(kc) * 512);      \
    } while (0)

#define COMP(bufi, bf)                                                                     \
    do {                                                                                   \
        _Pragma("unroll")                                                                  \
        for (int lt = 0; lt < 4; ++lt) {                                                   \
            short8 ahf = *(const short8*)(&smem[bufi][lt][lane << 3]);                     \
            short8 alf = *(const short8*)(&smem[bufi][4 + lt][lane << 3]);                 \
            __builtin_amdgcn_s_setprio(1);                                                 \
            _Pragma("unroll")                                                              \
            for (int pt = 0; pt < 2; ++pt) {                                               \
                acc[pt][lt] = __builtin_amdgcn_mfma_f32_32x32x16_bf16(bf[pt], ahf, acc[pt][lt], 0, 0, 0);     \
                acc[pt][lt] = __builtin_amdgcn_mfma_f32_32x32x16_bf16(bf[pt], alf, acc[pt][lt], 0, 0, 0);     \
                acc[pt][lt] = __builtin_amdgcn_mfma_f32_32x32x16_bf16(bf[2 + pt], ahf, acc[pt][lt], 0, 0, 0); \
            }                                                                              \
            __builtin_amdgcn_s_setprio(0);                                                 \
        }                                                                                  \
    } while (0)

    floatx16 acc[2][4];
#pragma unroll
    for (int i = 0; i < 2; ++i)
#pragma unroll
        for (int j = 0; j < 4; ++j)
#pragma unroll
            for (int r = 0; r < 16; ++r) acc[i][j][r] = 0.f;

    short8 bB0[4], bB1[4];
    LOADB(bB0, 0);                             // chunk 0 B -> regs   (4 vm ops)
    STAGEA(dst0, 0);                           // chunk 0 A -> LDS    (2 vm ops)

    for (int t = 0; t < 64; t += 2) {
        // ---- even chunk t: buf0 / bB0 ----
        LOADB(bB1, t + 1);                     // next B (4)
        STAGEA(dst1, t + 1);                   // next A (2)
        asm volatile("s_waitcnt vmcnt(6)" ::: "memory");   // chunk t landed
        __builtin_amdgcn_s_barrier();
        asm volatile("" ::: "memory");
        COMP(0, bB0);
        asm volatile("" ::: "memory");
        __builtin_amdgcn_s_barrier();
        // ---- odd chunk t+1: buf1 / bB1 ----
        if (t + 2 < 64) {
            LOADB(bB0, t + 2);
            STAGEA(dst0, t + 2);
            asm volatile("s_waitcnt vmcnt(6)" ::: "memory");
        } else {
            asm volatile("s_waitcnt vmcnt(0)" ::: "memory");
        }
        __builtin_amdgcn_s_barrier();
        asm volatile("" ::: "memory");
        COMP(1, bB1);
        asm volatile("" ::: "memory");
        __builtin_amdgcn_s_barrier();
    }
#undef STAGEA
#undef LOADB
#undef COMP

    int x = lane & 31, kg = lane >> 5;
    int pw0 = P0 + (w << 6);
#pragma unroll
    for (int pt = 0; pt < 2; ++pt)
#pragma unroll
        for (int lt = 0; lt < 4; ++lt)
#pragma unroll
            for (int r = 0; r < 16; ++r) {
                int p = pw0 + (pt << 5) + (r & 3) + ((r >> 2) << 3) + (kg << 2);
                int l = L0 + (lt << 5) + x;
                if (p < NP) Rt[((size_t)b * NP + p) * NL + l] = acc[pt][lt][r];
            }
}

// ------- kernel 5: fused diag1 + diag2 + mask + softmax, row output -------
// (verified R8 per-p version: best measured non-GEMM config)
__global__ __launch_bounds__(256) void softmax_fused_kernel(const float* __restrict__ Rt,
                                                            const float* __restrict__ mmkA,
                                                            const float* __restrict__ mmpA,
                                                            float* __restrict__ E) {
    __shared__ float ld0[1024], ld1[1024], ld2[1024];
    __shared__ float red[8];
    int p = blockIdx.x, b = blockIdx.y;
    int ph = p / PHW, pw = p - ph * PHW;
    int t = threadIdx.x;
    int lane = t & 63, w = t >> 6;
    int l0 = t << 2;

    bool okm = (p != 0), okp = (p != 3968);
    int Pm = (ph > 0) ? p - 63 : 3905 + pw;
    int Pp = (ph < 62) ? p + 63 : pw + 1;

    const float* Rb = Rt + (size_t)b * NP * NL;
#define BUILD(dst, q)                                                   \
    do {                                                                \
        const float* base = Rb + (size_t)(q) * NL;                      \
        float4 r = *(const float4*)(base + l0);                         \
        if ((q) > 0) {                                                  \
            const float* pm = base - NL;                                \
            r.x += (l0 > 0) ? pm[l0 - 1] : 0.f;                         \
            r.y += pm[l0];  r.z += pm[l0 + 1];  r.w += pm[l0 + 2];      \
        }                                                               \
        if ((q) < NP - 1) {                                             \
            const float* pp = base + NL;                                \
            r.x += pp[l0 + 1];  r.y += pp[l0 + 2];  r.z += pp[l0 + 3];  \
            r.w += (l0 + 4 < NL) ? pp[l0 + 4] : 0.f;                    \
        }                                                               \
        *(float4*)(dst + l0) = r;                                       \
    } while (0)

    BUILD(ld0, p);
    if (okm) BUILD(ld1, Pm);
    if (okp) BUILD(ld2, Pp);
#undef BUILD
    __syncthreads();

    float4 vc = *(const float4*)(ld0 + l0);
    float4 vm = {0.f, 0.f, 0.f, 0.f}, vp = {0.f, 0.f, 0.f, 0.f};
    if (okm) {
        if (l0 >= 32) vm = *(const float4*)(ld1 + l0 - 32);
        else {
            vm.x = (l0 == 0) ? 0.f : ld1[l0 + 991];
            vm.y = ld1[l0 + 992];
            vm.z = ld1[l0 + 993];
            vm.w = ld1[l0 + 994];
        }
    }
    if (okp) {
        if (l0 < 992) vp = *(const float4*)(ld2 + l0 + 32);
        else {
            vp.x = ld2[l0 - 991];
            vp.y = ld2[l0 - 990];
            vp.z = ld2[l0 - 989];
            vp.w = (l0 + 3 == 1023) ? 0.f : ld2[l0 - 988];
        }
    }
    float mmpv = mmpA[b * NP + p];
    float4 km = *(const float4*)(mmkA + b * NL + l0);
    float lg[4];
    float fsum[4] = {vc.x + vm.x + vp.x, vc.y + vm.y + vp.y,
                     vc.z + vm.z + vp.z, vc.w + vm.w + vp.w};
    float kk[4] = {km.x, km.y, km.z, km.w};
#pragma unroll
    for (int i = 0; i < 4; ++i) {
        float mmv = (((kk[i] > mmpv) && (mmpv > 0.5f)) || (kk[i] == 1.0f)) ? 1.0f : 0.0f;
        lg[i] = fsum[i] * mmv * 10.0f;
    }
    float mx = fmaxf(fmaxf(lg[0], lg[1]), fmaxf(lg[2], lg[3]));
#pragma unroll
    for (int off = 32; off >= 1; off >>= 1) mx = fmaxf(mx, __shfl_xor(mx, off, 64));
    if (lane == 0) red[w] = mx;
    __syncthreads();
    mx = fmaxf(fmaxf(red[0], red[1]), fmaxf(red[2], red[3]));
    float e[4];
    float s = 0.f;
#pragma unroll
    for (int i = 0; i < 4; ++i) { e[i] = expf(lg[i] - mx); s += e[i]; }
#pragma unroll
    for (int off = 32; off >= 1; off >>= 1) s += __shfl_xor(s, off, 64);
    if (lane == 0) red[4 + w] = s;
    __syncthreads();
    float rinv = 1.0f / (red[4] + red[5] + red[6] + red[7]);
    float4 ev = {e[0] * rinv, e[1] * rinv, e[2] * rinv, e[3] * rinv};
    *(float4*)(E + (((size_t)b * NP + p) << 10) + l0) = ev;
}

// ---------------- kernel 6: tiled transpose E[p][l] -> out[l][p] ----------
__global__ __launch_bounds__(256) void transpose_kernel(const float* __restrict__ E,
                                                        float* __restrict__ out) {
    __shared__ float tile[63 * 65];
    int pt = blockIdx.x;       // 0..62 : p0 = pt*63
    int lt = blockIdx.y;       // 0..15 : l0 = lt*64
    int b  = blockIdx.z;
    int t = threadIdx.x;
    int p0 = pt * 63, l0 = lt << 6;
    const float* Eb = E + ((size_t)b * NP << 10);
    {
        int j = t & 63, i4 = t >> 6;
#pragma unroll
        for (int k = 0; k < 16; ++k) {
            int i = (k << 2) + i4;
            if (i < 63) tile[i * 65 + j] = Eb[((size_t)(p0 + i) << 10) + l0 + j];
        }
    }
    __syncthreads();
    {
        int ii = t & 63, jj4 = t >> 6;
        if (ii < 63) {
#pragma unroll
            for (int k = 0; k < 16; ++k) {
                int jj = (k << 2) + jj4;
                out[((size_t)b * NL + l0 + jj) * NP + p0 + ii] = tile[ii * 65 + jj];
            }
        }
    }
}

extern "C" void kernel_launch(void* const* d_in, const int* in_sizes, int n_in,
                              void* d_out, int out_size, void* d_ws, size_t ws_size,
                              hipStream_t stream) {
    const float* f    = (const float*)d_in[0];
    const float* b    = (const float*)d_in[1];
    const float* mask = (const float*)d_in[2];
    float* out = (float*)d_out;

    // Rt lives in d_out (consumed by softmax before transpose overwrites out).
    float* Rt = (float*)d_out;

    // ws layout (floats): E at [16257024 .. 32514048); stats after.
    // A'/B' (~84 MB) occupy ws from 0 but are dead post-GEMM.
    float* wsf = (float*)d_ws;
    float* E  = wsf + 16257024;
    ushort_t* Ahi = (ushort_t*)d_ws;
    ushort_t* Alo = Ahi + (size_t)NB * A_BSTRIDE;
    ushort_t* Bhi = Alo + (size_t)NB * A_BSTRIDE;
    ushort_t* Blo = Bhi + (size_t)NB * B_BSTRIDE;
    float* invn = wsf + 32514048;
    float* mmk = invn + 256;
    float* mmp = mmk + 4096;

    prep_kernel<<<dim3(847), dim3(256), 0, stream>>>(b, mask, invn, mmk, mmp, Bhi, Blo);
    split_kernel<<<dim3(95, 4, 2), dim3(256), 0, stream>>>(b, invn, Ahi, Alo, f, Bhi, Blo);
    gemm_kernel<<<dim3(512), dim3(256), 0, stream>>>(Ahi, Alo, Bhi, Blo, Rt);
    softmax_fused_kernel<<<dim3(3969, 4), dim3(256), 0, stream>>>(Rt, mmk, mmp, E);
    transpose_kernel<<<dim3(63, 16, 4), dim3(256), 0, stream>>>(E, out);
}